// Round 5
// baseline (36.721 us; speedup 1.0000x reference)
//
#include <hip/hip_runtime.h>

#define HIDDEN 768
#define LN_EPS 1e-5f

typedef float f32x4 __attribute__((ext_vector_type(4)));

// DIAGNOSTIC ROUND: same kernel as round 1/2 (one 64-lane wave per row),
// launched TWICE back-to-back in the same graph. Incremental time of the
// second (warm-cache, no-extra-graph-overhead) launch separates
// "pure bandwidth floor" from "kernel + fixed replay overhead".
// Output is idempotent: both launches write identical values.
__global__ __launch_bounds__(256) void bert_embedding_kernel(
    const int* __restrict__ input_ids,
    const int* __restrict__ token_type_ids,
    const float* __restrict__ tok_w,
    const float* __restrict__ pos_w,
    const float* __restrict__ type_w,
    const float* __restrict__ gamma,
    const float* __restrict__ beta,
    float* __restrict__ out,
    int n_rows, int S)
{
    const int wave = (blockIdx.x * blockDim.x + threadIdx.x) >> 6;
    const int lane = threadIdx.x & 63;
    if (wave >= n_rows) return;

    const int s = wave % S;
    const int tok = input_ids[wave];
    const int typ = token_type_ids[wave];

    const f32x4* __restrict__ tw = reinterpret_cast<const f32x4*>(tok_w  + (size_t)tok * HIDDEN);
    const f32x4* __restrict__ pw = reinterpret_cast<const f32x4*>(pos_w  + (size_t)s   * HIDDEN);
    const f32x4* __restrict__ yw = reinterpret_cast<const f32x4*>(type_w + (size_t)typ * HIDDEN);

    f32x4 e[3];
    float sum = 0.f, sumsq = 0.f;
    #pragma unroll
    for (int k = 0; k < 3; ++k) {
        const int idx = lane + k * 64;
        const f32x4 a = tw[idx];
        const f32x4 b = pw[idx];
        const f32x4 c = yw[idx];
        f32x4 v = a + b + c;
        e[k] = v;
        sum   += v.x + v.y + v.z + v.w;
        sumsq += v.x * v.x + v.y * v.y + v.z * v.z + v.w * v.w;
    }

    #pragma unroll
    for (int m = 1; m < 64; m <<= 1) {
        sum   += __shfl_xor(sum, m);
        sumsq += __shfl_xor(sumsq, m);
    }

    const float inv_h = 1.0f / (float)HIDDEN;
    const float mean = sum * inv_h;
    const float var  = sumsq * inv_h - mean * mean;
    const float rs   = rsqrtf(var + LN_EPS);

    f32x4* __restrict__ o = reinterpret_cast<f32x4*>(out + (size_t)wave * HIDDEN);
    const f32x4* __restrict__ g4 = reinterpret_cast<const f32x4*>(gamma);
    const f32x4* __restrict__ b4 = reinterpret_cast<const f32x4*>(beta);

    #pragma unroll
    for (int k = 0; k < 3; ++k) {
        const int idx = lane + k * 64;
        const f32x4 g  = g4[idx];
        const f32x4 bb = b4[idx];
        const f32x4 v  = e[k];
        f32x4 r;
        r.x = (v.x - mean) * rs * g.x + bb.x;
        r.y = (v.y - mean) * rs * g.y + bb.y;
        r.z = (v.z - mean) * rs * g.z + bb.z;
        r.w = (v.w - mean) * rs * g.w + bb.w;
        __builtin_nontemporal_store(r, &o[idx]);
    }
}

extern "C" void kernel_launch(void* const* d_in, const int* in_sizes, int n_in,
                              void* d_out, int out_size, void* d_ws, size_t ws_size,
                              hipStream_t stream) {
    const int*   input_ids      = (const int*)d_in[0];
    const int*   token_type_ids = (const int*)d_in[1];
    const float* tok_w          = (const float*)d_in[2];
    const float* pos_w          = (const float*)d_in[3];
    const float* type_w         = (const float*)d_in[4];
    const float* gamma          = (const float*)d_in[5];
    const float* beta           = (const float*)d_in[6];
    float* out = (float*)d_out;

    const int n_rows = in_sizes[0];          // B * S = 16384
    const int S = in_sizes[3] / HIDDEN;      // pos_w rows = 512

    const int waves_per_block = 4;           // 256 threads
    const int blocks = (n_rows + waves_per_block - 1) / waves_per_block;

    // Launch 1: "cold" (as in all prior rounds).
    bert_embedding_kernel<<<blocks, 256, 0, stream>>>(
        input_ids, token_type_ids, tok_w, pos_w, type_w, gamma, beta,
        out, n_rows, S);
    // Launch 2: warm caches, zero extra graph-launch overhead. Idempotent.
    bert_embedding_kernel<<<blocks, 256, 0, stream>>>(
        input_ids, token_type_ids, tok_w, pos_w, type_w, gamma, beta,
        out, n_rows, S);
}

// Round 6
// 21.004 us; speedup vs baseline: 1.7482x; 1.7482x over previous
//
#include <hip/hip_runtime.h>

#define HIDDEN 768
#define LN_EPS 1e-5f

typedef float f32x4 __attribute__((ext_vector_type(4)));

// Final kernel: one 64-lane wave per token row (16384 rows). Each lane
// handles 3 float4 (12 floats) at float4 index = lane + k*64 (coalesced
// 16 B/lane). Three gathers summed in registers, wave-wide shuffle
// reduction for mean/var, normalize, nontemporal float4 stores.
//
// Roofline accounting (measured via 2x-launch diagnostic, round 5):
//   warm kernel time 15.7 us  ~=  (~48 MB gathered reads + 50 MB writes)
//   at ~6.3 TB/s achievable mixed HBM BW (14.4-15.9 us model window).
//   Scored time adds ~5.3 us fixed graph-replay overhead. Four kernel
//   structures (1 row/wave, 2 rows/wave, ping-pong prefetch, NT stores)
//   all land at 21 +/- 0.5 us -> bandwidth floor, not latency/occupancy.
__global__ __launch_bounds__(256) void bert_embedding_kernel(
    const int* __restrict__ input_ids,
    const int* __restrict__ token_type_ids,
    const float* __restrict__ tok_w,
    const float* __restrict__ pos_w,
    const float* __restrict__ type_w,
    const float* __restrict__ gamma,
    const float* __restrict__ beta,
    float* __restrict__ out,
    int n_rows, int S)
{
    const int wave = (blockIdx.x * blockDim.x + threadIdx.x) >> 6;
    const int lane = threadIdx.x & 63;
    if (wave >= n_rows) return;

    const int s = wave % S;
    const int tok = input_ids[wave];
    const int typ = token_type_ids[wave];

    const f32x4* __restrict__ tw = reinterpret_cast<const f32x4*>(tok_w  + (size_t)tok * HIDDEN);
    const f32x4* __restrict__ pw = reinterpret_cast<const f32x4*>(pos_w  + (size_t)s   * HIDDEN);
    const f32x4* __restrict__ yw = reinterpret_cast<const f32x4*>(type_w + (size_t)typ * HIDDEN);

    f32x4 e[3];
    float sum = 0.f, sumsq = 0.f;
    #pragma unroll
    for (int k = 0; k < 3; ++k) {
        const int idx = lane + k * 64;
        const f32x4 a = tw[idx];
        const f32x4 b = pw[idx];
        const f32x4 c = yw[idx];
        f32x4 v = a + b + c;
        e[k] = v;
        sum   += v.x + v.y + v.z + v.w;
        sumsq += v.x * v.x + v.y * v.y + v.z * v.z + v.w * v.w;
    }

    #pragma unroll
    for (int m = 1; m < 64; m <<= 1) {
        sum   += __shfl_xor(sum, m);
        sumsq += __shfl_xor(sumsq, m);
    }

    const float inv_h = 1.0f / (float)HIDDEN;
    const float mean = sum * inv_h;
    const float var  = sumsq * inv_h - mean * mean;
    const float rs   = rsqrtf(var + LN_EPS);

    f32x4* __restrict__ o = reinterpret_cast<f32x4*>(out + (size_t)wave * HIDDEN);
    const f32x4* __restrict__ g4 = reinterpret_cast<const f32x4*>(gamma);
    const f32x4* __restrict__ b4 = reinterpret_cast<const f32x4*>(beta);

    #pragma unroll
    for (int k = 0; k < 3; ++k) {
        const int idx = lane + k * 64;
        const f32x4 g  = g4[idx];
        const f32x4 bb = b4[idx];
        const f32x4 v  = e[k];
        f32x4 r;
        r.x = (v.x - mean) * rs * g.x + bb.x;
        r.y = (v.y - mean) * rs * g.y + bb.y;
        r.z = (v.z - mean) * rs * g.z + bb.z;
        r.w = (v.w - mean) * rs * g.w + bb.w;
        __builtin_nontemporal_store(r, &o[idx]);
    }
}

extern "C" void kernel_launch(void* const* d_in, const int* in_sizes, int n_in,
                              void* d_out, int out_size, void* d_ws, size_t ws_size,
                              hipStream_t stream) {
    const int*   input_ids      = (const int*)d_in[0];
    const int*   token_type_ids = (const int*)d_in[1];
    const float* tok_w          = (const float*)d_in[2];
    const float* pos_w          = (const float*)d_in[3];
    const float* type_w         = (const float*)d_in[4];
    const float* gamma          = (const float*)d_in[5];
    const float* beta           = (const float*)d_in[6];
    float* out = (float*)d_out;

    const int n_rows = in_sizes[0];          // B * S = 16384
    const int S = in_sizes[3] / HIDDEN;      // pos_w rows = 512

    const int waves_per_block = 4;           // 256 threads
    const int blocks = (n_rows + waves_per_block - 1) / waves_per_block;
    bert_embedding_kernel<<<blocks, 256, 0, stream>>>(
        input_ids, token_type_ids, tok_w, pos_w, type_w, gamma, beta,
        out, n_rows, S);
}